// Round 4
// baseline (193.145 us; speedup 1.0000x reference)
//
#include <hip/hip_runtime.h>
#include <hip/hip_bf16.h>
#include <stdint.h>

#define IN_F 4096
#define OUT_F 11008
#define NUM_CH 128
#define NUM_NORM 3968
#define BATCH 64
#define KSPLIT 8
#define KCHUNK (IN_F / KSPLIT)   // 512
#define NSTEP (KCHUNK / 32)      // 16

typedef short short8 __attribute__((ext_vector_type(8)));
typedef float float4v __attribute__((ext_vector_type(4)));

__device__ __forceinline__ unsigned short f2bf(float f) {
    union { float f; unsigned u; } v; v.f = f;
    unsigned u = v.u;
    return (unsigned short)((u + 0x7FFFu + ((u >> 16) & 1u)) >> 16);
}

__device__ __forceinline__ unsigned pk_bf16(float lo, float hi) {
    __hip_bfloat162 h = __float22bfloat162_rn(make_float2(lo, hi));  // v_cvt_pk_bf16_f32
    union { __hip_bfloat162 h; unsigned u; } c; c.h = h; return c.u;
}

// out[m][n] = bias[n]  (pre-init so qgemm can atomicAdd partials)
__global__ __launch_bounds__(256) void init_out(
        const float* __restrict__ bias, float* __restrict__ out) {
    const int i = blockIdx.x * 256 + threadIdx.x;        // float4 index
    const int c = i % (OUT_F / 4);
    const float4v b4 = *reinterpret_cast<const float4v*>(bias + c * 4);
    reinterpret_cast<float4v*>(out)[i] = b4;
}

// Gather-permute x into bf16 xp[64][4096]:
//   pos j in [0,3968): x[:, normal_idx[j]]   pos 3968+c: x[:, cherry_indices[c]]
__global__ __launch_bounds__(256) void permute_x(
        const float* __restrict__ x, const int* __restrict__ cidx,
        unsigned short* __restrict__ xp) {
    int i = blockIdx.x * blockDim.x + threadIdx.x;
    int b = blockIdx.y;
    int lo = 0, hi = NUM_CH;
    while (lo < hi) { int mid = (lo + hi) >> 1; if (cidx[mid] < i) lo = mid + 1; else hi = mid; }
    bool isch = (lo < NUM_CH) && (cidx[lo] == i);
    int pos = isch ? (NUM_NORM + lo) : (i - lo);
    xp[b * IN_F + pos] = f2bf(x[b * IN_F + i]);
}

// Barrier-free fused dequant + bf16 MFMA GEMM.
// Wave owns a 16-wide n-tile; lane dequants its B fragment directly from
// qweight column nw into registers (no LDS). 4 MFMAs/step cover all 64 m.
__global__ __launch_bounds__(256, 4) void qgemm(
        const unsigned short* __restrict__ xp, const int* __restrict__ qw,
        const float* __restrict__ cw, const float* __restrict__ scales,
        float* __restrict__ out) {
    const int tid  = threadIdx.x;
    const int wave = tid >> 6;
    const int lane = tid & 63;
    const int ln   = lane & 15;   // n within wave tile / m within m-tile (A)
    const int lq   = lane >> 4;   // k-quad

    const int nw    = blockIdx.x * 64 + wave * 16 + ln;  // this lane's n column
    const int kbase = blockIdx.y * KCHUNK;

    const int*   qcol = qw + nw;
    const float* scol = scales + nw;
    const float* ccol = cw + nw;

    float4v acc[4];
    #pragma unroll
    for (int s = 0; s < 4; ++s) acc[s] = (float4v){0.f, 0.f, 0.f, 0.f};

    // ---- prologue: stage step 0 (chunk starts are always in the normal region) ----
    int qn0, qn1, qn2, qn3; float scn;
    {
        const int rb = (kbase + lq * 8) >> 1;
        scn = scol[(size_t)(kbase >> 7) * OUT_F];
        qn0 = qcol[(size_t)(rb + 0) * OUT_F];
        qn1 = qcol[(size_t)(rb + 1) * OUT_F];
        qn2 = qcol[(size_t)(rb + 2) * OUT_F];
        qn3 = qcol[(size_t)(rb + 3) * OUT_F];
    }
    short8 a_cur[4];
    #pragma unroll
    for (int mt = 0; mt < 4; ++mt)
        a_cur[mt] = *reinterpret_cast<const short8*>(
            xp + (size_t)(mt * 16 + ln) * IN_F + kbase + lq * 8);

    for (int step = 0; step < NSTEP; ++step) {
        const int k0 = kbase + (step << 5);
        union { short8 s; unsigned u[4]; } bb;

        if (k0 < NUM_NORM) {
            const int q0 = qn0, q1 = qn1, q2 = qn2, q3 = qn3;
            const float sc = scn;
            // prefetch next step's q-words while we dequant/MFMA this one
            const int kn = k0 + 32;
            if (step + 1 < NSTEP && kn < NUM_NORM) {
                const int rb = (kn + lq * 8) >> 1;
                scn = scol[(size_t)(kn >> 7) * OUT_F];
                qn0 = qcol[(size_t)(rb + 0) * OUT_F];
                qn1 = qcol[(size_t)(rb + 1) * OUT_F];
                qn2 = qcol[(size_t)(rb + 2) * OUT_F];
                qn3 = qcol[(size_t)(rb + 3) * OUT_F];
            }
            bb.u[0] = pk_bf16((float)((q0 & 0xF) - 8) * sc, (float)(((q0 >> 4) & 0xF) - 8) * sc);
            bb.u[1] = pk_bf16((float)((q1 & 0xF) - 8) * sc, (float)(((q1 >> 4) & 0xF) - 8) * sc);
            bb.u[2] = pk_bf16((float)((q2 & 0xF) - 8) * sc, (float)(((q2 >> 4) & 0xF) - 8) * sc);
            bb.u[3] = pk_bf16((float)((q3 & 0xF) - 8) * sc, (float)(((q3 >> 4) & 0xF) - 8) * sc);
        } else {
            // cherry region (last 4 steps of the last chunk only), load inline
            const int kr = k0 + lq * 8 - NUM_NORM;
            float c[8];
            #pragma unroll
            for (int j = 0; j < 8; ++j) c[j] = ccol[(size_t)(kr + j) * OUT_F];
            #pragma unroll
            for (int r = 0; r < 4; ++r) bb.u[r] = pk_bf16(c[2 * r], c[2 * r + 1]);
        }

        const short8 a0 = a_cur[0], a1 = a_cur[1], a2 = a_cur[2], a3 = a_cur[3];
        if (step + 1 < NSTEP) {
            const int kn = k0 + 32;
            #pragma unroll
            for (int mt = 0; mt < 4; ++mt)
                a_cur[mt] = *reinterpret_cast<const short8*>(
                    xp + (size_t)(mt * 16 + ln) * IN_F + kn + lq * 8);
        }

        acc[0] = __builtin_amdgcn_mfma_f32_16x16x32_bf16(a0, bb.s, acc[0], 0, 0, 0);
        acc[1] = __builtin_amdgcn_mfma_f32_16x16x32_bf16(a1, bb.s, acc[1], 0, 0, 0);
        acc[2] = __builtin_amdgcn_mfma_f32_16x16x32_bf16(a2, bb.s, acc[2], 0, 0, 0);
        acc[3] = __builtin_amdgcn_mfma_f32_16x16x32_bf16(a3, bb.s, acc[3], 0, 0, 0);
    }

    // Epilogue: D row = lq*4+r -> m within m-tile, col = ln -> n (verified layout)
    #pragma unroll
    for (int mt = 0; mt < 4; ++mt) {
        #pragma unroll
        for (int r = 0; r < 4; ++r) {
            const int m = mt * 16 + (lq << 2) + r;
            atomicAdd(&out[(size_t)m * OUT_F + nw], acc[mt][r]);
        }
    }
}

extern "C" void kernel_launch(void* const* d_in, const int* in_sizes, int n_in,
                              void* d_out, int out_size, void* d_ws, size_t ws_size,
                              hipStream_t stream) {
    const float* x      = (const float*)d_in[0];
    const int*   qw     = (const int*)d_in[1];     // uint8 widened to int32 by harness
    const float* cw     = (const float*)d_in[2];
    const int*   cidx   = (const int*)d_in[3];
    const float* scales = (const float*)d_in[4];
    const float* bias   = (const float*)d_in[5];
    float*       out    = (float*)d_out;
    unsigned short* xp  = (unsigned short*)d_ws;   // 64*4096 bf16 = 512 KB

    init_out<<<(BATCH * OUT_F / 4) / 256, 256, 0, stream>>>(bias, out);
    dim3 pgrid(IN_F / 256, BATCH);
    permute_x<<<pgrid, 256, 0, stream>>>(x, cidx, xp);
    qgemm<<<dim3(OUT_F / 64, KSPLIT), 256, 0, stream>>>(xp, qw, cw, scales, out);
}

// Round 5
// 164.210 us; speedup vs baseline: 1.1762x; 1.1762x over previous
//
#include <hip/hip_runtime.h>
#include <hip/hip_bf16.h>
#include <stdint.h>

#define IN_F 4096
#define OUT_F 11008
#define NUM_CH 128
#define NUM_NORM 3968
#define BATCH 64
#define KSPLIT 8
#define KCHUNK (IN_F / KSPLIT)   // 512
#define NMEGA (KCHUNK / 128)     // 4 megasteps of K=128 per block
#define BS 136                   // LDS k-stride in shorts (conflict-free, 16B-aligned)

typedef short short8 __attribute__((ext_vector_type(8)));
typedef float float4v __attribute__((ext_vector_type(4)));
typedef int int4v __attribute__((ext_vector_type(4)));

__device__ __forceinline__ unsigned short f2bf(float f) {
    union { float f; unsigned u; } v; v.f = f;
    unsigned u = v.u;
    return (unsigned short)((u + 0x7FFFu + ((u >> 16) & 1u)) >> 16);
}

__device__ __forceinline__ unsigned pk_bf16(float lo, float hi) {
    __hip_bfloat162 h = __float22bfloat162_rn(make_float2(lo, hi));  // v_cvt_pk_bf16_f32
    union { __hip_bfloat162 h; unsigned u; } c; c.h = h; return c.u;
}

// out[m][n] = bias[n]  (pre-init so qgemm can atomicAdd partials)
__global__ __launch_bounds__(256) void init_out(
        const float* __restrict__ bias, float* __restrict__ out) {
    const int i = blockIdx.x * 256 + threadIdx.x;        // float4 index
    const int c = i % (OUT_F / 4);
    const float4v b4 = *reinterpret_cast<const float4v*>(bias + c * 4);
    reinterpret_cast<float4v*>(out)[i] = b4;
}

// Gather-permute x into bf16 xp[64][4096]:
//   pos j in [0,3968): x[:, normal_idx[j]]   pos 3968+c: x[:, cherry_indices[c]]
__global__ __launch_bounds__(256) void permute_x(
        const float* __restrict__ x, const int* __restrict__ cidx,
        unsigned short* __restrict__ xp) {
    int i = blockIdx.x * blockDim.x + threadIdx.x;
    int b = blockIdx.y;
    int lo = 0, hi = NUM_CH;
    while (lo < hi) { int mid = (lo + hi) >> 1; if (cidx[mid] < i) lo = mid + 1; else hi = mid; }
    bool isch = (lo < NUM_CH) && (cidx[lo] == i);
    int pos = isch ? (NUM_NORM + lo) : (i - lo);
    xp[b * IN_F + pos] = f2bf(x[b * IN_F + i]);
}

// Fused dequant + bf16 MFMA GEMM.
// K-megastep = 128, double-buffered bf16 LDS B-tile, ONE barrier per megastep,
// global->reg prefetch issued a full megastep ahead (vmcnt wait lands after
// ~600 cyc of compute). Staging: thread loads 4 consecutive packed rows x 4
// cols (dwordx4, coalesced), dequants once per block, ds_write_b128.
__global__ __launch_bounds__(256, 4) void qgemm(
        const unsigned short* __restrict__ xp, const int* __restrict__ qw,
        const float* __restrict__ cw, const float* __restrict__ scales,
        float* __restrict__ out) {
    __shared__ unsigned short Bt[2][64][BS];   // 2 x 17 KB

    const int tid  = threadIdx.x;
    const int wave = tid >> 6;
    const int lane = tid & 63;
    const int ln   = lane & 15;
    const int lq   = lane >> 4;
    const int n0    = blockIdx.x * 64;
    const int kbase = blockIdx.y * KCHUNK;
    const int tcol = (tid & 15) << 2;   // staging col offset 0..60
    const int trow = tid >> 4;          // staging row group 0..15

    const int*   qbase = qw + n0 + tcol;
    const float* sbase = scales + n0 + tcol;
    const float* cbase = cw + n0 + tcol;

    float4v acc[4];
    #pragma unroll
    for (int s = 0; s < 4; ++s) acc[s] = (float4v){0.f, 0.f, 0.f, 0.f};

    // ---- prologue: issue loads for megastep 0 (always normal region) ----
    int4v qcur[4]; float4v scur;
    {
        const int rb = (kbase >> 1) + 4 * trow;
        #pragma unroll
        for (int i = 0; i < 4; ++i)
            qcur[i] = *reinterpret_cast<const int4v*>(qbase + (size_t)(rb + i) * OUT_F);
        scur = *reinterpret_cast<const float4v*>(sbase + (size_t)(kbase >> 7) * OUT_F);
    }

    for (int s = 0; s < NMEGA; ++s) {
        const int k0 = kbase + s * 128;
        unsigned short (*buf)[BS] = Bt[s & 1];

        if (k0 < NUM_NORM) {
            const int4v q0 = qcur[0], q1 = qcur[1], q2 = qcur[2], q3 = qcur[3];
            const float4v sc = scur;
            // prefetch next megastep's raw data (latency hidden by this
            // megastep's dequant + MFMA work)
            const int kn = k0 + 128;
            if (s + 1 < NMEGA && kn < NUM_NORM) {
                const int rb = (kn >> 1) + 4 * trow;
                #pragma unroll
                for (int i = 0; i < 4; ++i)
                    qcur[i] = *reinterpret_cast<const int4v*>(qbase + (size_t)(rb + i) * OUT_F);
                scur = *reinterpret_cast<const float4v*>(sbase + (size_t)(kn >> 7) * OUT_F);
            }
            const int4v qq[4] = {q0, q1, q2, q3};
            #pragma unroll
            for (int cc = 0; cc < 4; ++cc) {
                union { short8 v; unsigned u[4]; } wv;
                const float s1 = sc[cc];
                #pragma unroll
                for (int i = 0; i < 4; ++i) {
                    const int q = qq[i][cc];
                    wv.u[i] = pk_bf16((float)((q & 0xF) - 8) * s1,
                                      (float)(((q >> 4) & 0xF) - 8) * s1);
                }
                *reinterpret_cast<short8*>(&buf[tcol + cc][trow * 8]) = wv.v;
            }
        } else {
            // pure-cherry megastep (k0 == NUM_NORM; only block ky==7, s==3)
            float4v ch[8];
            #pragma unroll
            for (int j = 0; j < 8; ++j)
                ch[j] = *reinterpret_cast<const float4v*>(
                    cbase + (size_t)(8 * trow + j) * OUT_F);
            #pragma unroll
            for (int cc = 0; cc < 4; ++cc) {
                union { short8 v; unsigned u[4]; } wv;
                #pragma unroll
                for (int m = 0; m < 4; ++m)
                    wv.u[m] = pk_bf16(ch[2 * m][cc], ch[2 * m + 1][cc]);
                *reinterpret_cast<short8*>(&buf[tcol + cc][trow * 8]) = wv.v;
            }
        }

        __syncthreads();   // the ONLY barrier per megastep (dbuf covers WAR)

        // A fragments for all 4 k-substeps (xp is L2-hot)
        const unsigned short* xprow =
            xp + (size_t)((wave << 4) + ln) * IN_F + k0 + (lq << 3);
        const short8 a0 = *reinterpret_cast<const short8*>(xprow);
        const short8 a1 = *reinterpret_cast<const short8*>(xprow + 32);
        const short8 a2 = *reinterpret_cast<const short8*>(xprow + 64);
        const short8 a3 = *reinterpret_cast<const short8*>(xprow + 96);

        #pragma unroll
        for (int st = 0; st < 4; ++st) {
            const unsigned short* bp = &buf[(st << 4) + ln][lq << 3];
            acc[st] = __builtin_amdgcn_mfma_f32_16x16x32_bf16(
                a0, *reinterpret_cast<const short8*>(bp), acc[st], 0, 0, 0);
            acc[st] = __builtin_amdgcn_mfma_f32_16x16x32_bf16(
                a1, *reinterpret_cast<const short8*>(bp + 32), acc[st], 0, 0, 0);
            acc[st] = __builtin_amdgcn_mfma_f32_16x16x32_bf16(
                a2, *reinterpret_cast<const short8*>(bp + 64), acc[st], 0, 0, 0);
            acc[st] = __builtin_amdgcn_mfma_f32_16x16x32_bf16(
                a3, *reinterpret_cast<const short8*>(bp + 96), acc[st], 0, 0, 0);
        }
    }

    // Epilogue: D col = ln (n), row = lq*4 + r (m); atomic partial accumulate
    #pragma unroll
    for (int st = 0; st < 4; ++st) {
        const int n = n0 + (st << 4) + ln;
        #pragma unroll
        for (int r = 0; r < 4; ++r) {
            const int m = (wave << 4) + (lq << 2) + r;
            atomicAdd(&out[(size_t)m * OUT_F + n], acc[st][r]);
        }
    }
}

extern "C" void kernel_launch(void* const* d_in, const int* in_sizes, int n_in,
                              void* d_out, int out_size, void* d_ws, size_t ws_size,
                              hipStream_t stream) {
    const float* x      = (const float*)d_in[0];
    const int*   qw     = (const int*)d_in[1];     // uint8 widened to int32 by harness
    const float* cw     = (const float*)d_in[2];
    const int*   cidx   = (const int*)d_in[3];
    const float* scales = (const float*)d_in[4];
    const float* bias   = (const float*)d_in[5];
    float*       out    = (float*)d_out;
    unsigned short* xp  = (unsigned short*)d_ws;   // 64*4096 bf16 = 512 KB

    init_out<<<(BATCH * OUT_F / 4) / 256, 256, 0, stream>>>(bias, out);
    dim3 pgrid(IN_F / 256, BATCH);
    permute_x<<<pgrid, 256, 0, stream>>>(x, cidx, xp);
    qgemm<<<dim3(OUT_F / 64, KSPLIT), 256, 0, stream>>>(xp, qw, cw, scales, out);
}